// Round 3
// baseline (338.541 us; speedup 1.0000x reference)
//
#include <hip/hip_runtime.h>
#include <hip/hip_bf16.h>

// VeRA: out = SCALE * d_B[o] * ((x @ (d_A*A)^T) @ B^T)
// GEMM1 (split-K=4): part[s] = x @ Ab^T over K-chunk  (M=8192,N=256,K=1024 each)
// reduce: t = bf16(sum_s part[s])
// GEMM2: out = SCALE*d_B * (t @ Bb^T)  (M=8192,N=4096,K=256)
//
// R3: gemm1 takes full N=256 per block (x staged once, 32 MFMA/K-step,
// half the barrier drains). gemm2 stages the entire K=256 in one shot ->
// ONE barrier per block, no dbuf, 8192 small blocks for write overlap.
// T2 swizzle kept everywhere (conflicts measured 0).

#define SCALE_F 0.125f
#define M_TOT 8192
#define K_IN 4096
#define RANK 256
#define N_OUT 4096
#define S_SPLIT 4
#define KC 1024   // K_IN / S_SPLIT

typedef __bf16 bf16_t;
typedef __bf16 bf16x8 __attribute__((ext_vector_type(8)));
typedef __bf16 bf16x4 __attribute__((ext_vector_type(4)));
typedef float f32x4 __attribute__((ext_vector_type(4)));

typedef __attribute__((address_space(3))) unsigned int lds_u32_t;
typedef const __attribute__((address_space(1))) unsigned int glob_u32_t;

__device__ __forceinline__ void async16(const void* g, void* l) {
    __builtin_amdgcn_global_load_lds((glob_u32_t*)g, (lds_u32_t*)l, 16, 0, 0);
}

// ---- convert A (fold d_A) and B to bf16, fused ----
__global__ __launch_bounds__(256) void conv_AB(const float* __restrict__ A,
                                               const float* __restrict__ dA,
                                               const float* __restrict__ B,
                                               bf16_t* __restrict__ Ab,
                                               bf16_t* __restrict__ Bb) {
    int b = blockIdx.x;
    if (b < 1024) {
        int idx = b * 256 + threadIdx.x;
        float4 v = ((const float4*)A)[idx];
        float s = dA[idx >> 10];
        bf16x4 o;
        o.x = (bf16_t)(v.x * s); o.y = (bf16_t)(v.y * s);
        o.z = (bf16_t)(v.z * s); o.w = (bf16_t)(v.w * s);
        ((bf16x4*)Ab)[idx] = o;
    } else {
        int idx = (b - 1024) * 256 + threadIdx.x;
        float4 v = ((const float4*)B)[idx];
        bf16x4 o;
        o.x = (bf16_t)v.x; o.y = (bf16_t)v.y;
        o.z = (bf16_t)v.z; o.w = (bf16_t)v.w;
        ((bf16x4*)Bb)[idx] = o;
    }
}

// ---- GEMM1: part[z][8192][256] = x(fp32) @ Ab^T over K-chunk z ----
// BM=64, BN=256 (full rank), BK=64. grid (128, 4-z) = 512 blocks, 2/CU.
// 4 waves 2x2, wave tile 32x128 -> 32 MFMA per K-step per wave-pair.
// sA via async16 (linear LDS dest, pre-swizzled global source); sX reg-staged
// f32->bf16 with issue-early/write-late. 80 KB LDS.
__global__ __launch_bounds__(256) void gemm1(const float* __restrict__ x,
                                             const bf16_t* __restrict__ Ab,
                                             bf16_t* __restrict__ part) {
    __shared__ bf16_t sX[2][64 * 64];     // 8 KB each
    __shared__ bf16_t sA[2][256 * 64];    // 32 KB each; total 80 KB
    const int tid = threadIdx.x;
    const int lane = tid & 63, wave = tid >> 6;
    const int wm = wave >> 1, wn = wave & 1;
    const int l15 = lane & 15, quad = lane >> 4;
    const int bm = blockIdx.x * 64;
    const int k0 = blockIdx.y * KC;

    f32x4 acc[2][8];   // [m-frag][n-frag], frag holds 4 consecutive n
    const f32x4 zero = {0.f, 0.f, 0.f, 0.f};
    #pragma unroll
    for (int i = 0; i < 2; i++)
        #pragma unroll
        for (int j = 0; j < 8; j++) acc[i][j] = zero;

    f32x4 xr[2][2];   // in-flight x tile

    auto issue_x = [&](int kk) {
        #pragma unroll
        for (int c = 0; c < 2; c++) {
            int idx = c * 256 + tid;
            int row = idx >> 3, sl = idx & 7;
            const float* sp = &x[(size_t)(bm + row) * K_IN + kk + sl * 8];
            xr[c][0] = *(const f32x4*)sp;
            xr[c][1] = *(const f32x4*)(sp + 4);
        }
    };
    auto stage_a = [&](int b, int kk) {   // 256 rows x 8 slots, 8 passes
        #pragma unroll
        for (int c = 0; c < 8; c++) {
            int idx = c * 256 + tid;
            int row = idx >> 3, sl = idx & 7;
            async16(&Ab[(size_t)row * K_IN + kk + ((sl ^ (row & 7)) << 3)],
                    &sA[b][idx * 8]);
        }
    };
    auto write_x = [&](int b) {
        #pragma unroll
        for (int c = 0; c < 2; c++) {
            int idx = c * 256 + tid;
            int row = idx >> 3, sl = idx & 7;
            bf16x8 o;
            #pragma unroll
            for (int e = 0; e < 4; e++) {
                o[e]     = (bf16_t)xr[c][0][e];
                o[e + 4] = (bf16_t)xr[c][1][e];
            }
            *(bf16x8*)&sX[b][row * 64 + ((sl ^ (row & 7)) << 3)] = o;
        }
    };
    auto compute = [&](int b) {
        #pragma unroll
        for (int ks = 0; ks < 2; ks++) {
            bf16x8 af[2], bfr[8];
            #pragma unroll
            for (int i = 0; i < 2; i++) {
                int row = wm * 32 + i * 16 + l15;
                af[i] = *(const bf16x8*)&sX[b][row * 64 + ((((ks << 2) | quad) ^ (row & 7)) << 3)];
            }
            #pragma unroll
            for (int j = 0; j < 8; j++) {
                int row = wn * 128 + j * 16 + l15;
                bfr[j] = *(const bf16x8*)&sA[b][row * 64 + ((((ks << 2) | quad) ^ (row & 7)) << 3)];
            }
            // swapped operands: lane&15 = m-row, quad*4+r = n-col
            #pragma unroll
            for (int i = 0; i < 2; i++)
                #pragma unroll
                for (int j = 0; j < 8; j++)
                    acc[i][j] = __builtin_amdgcn_mfma_f32_16x16x32_bf16(bfr[j], af[i], acc[i][j], 0, 0, 0);
        }
    };

    issue_x(k0);
    stage_a(0, k0);
    write_x(0);
    __syncthreads();

    int cur = 0;
    for (int it = 1; it < KC / 64; ++it) {
        const int nxt = cur ^ 1;
        const int kk = k0 + it * 64;
        issue_x(kk);          // global->reg, hidden under compute
        stage_a(nxt, kk);     // global->LDS DMA, hidden under compute
        compute(cur);
        write_x(nxt);         // vmcnt wait for xr, then ds_write
        __syncthreads();
        cur = nxt;
    }
    compute(cur);

    bf16_t* p = part + (size_t)blockIdx.y * (M_TOT * RANK);
    #pragma unroll
    for (int i = 0; i < 2; i++) {
        int row = bm + wm * 32 + i * 16 + l15;
        #pragma unroll
        for (int j = 0; j < 8; j++) {
            int col = wn * 128 + j * 16 + quad * 4;
            bf16x4 o;
            #pragma unroll
            for (int r = 0; r < 4; r++) o[r] = (bf16_t)acc[i][j][r];
            *(bf16x4*)&p[(size_t)row * RANK + col] = o;
        }
    }
}

// ---- reduce: t = bf16(sum_z part[z]) ----
__global__ __launch_bounds__(256) void reduce_t(const bf16_t* __restrict__ part,
                                                bf16_t* __restrict__ t) {
    int i = (blockIdx.x * 256 + threadIdx.x) * 8;
    float s[8] = {0.f, 0.f, 0.f, 0.f, 0.f, 0.f, 0.f, 0.f};
    #pragma unroll
    for (int z = 0; z < S_SPLIT; z++) {
        bf16x8 v = *(const bf16x8*)&part[(size_t)z * M_TOT * RANK + i];
        #pragma unroll
        for (int e = 0; e < 8; e++) s[e] += (float)v[e];
    }
    bf16x8 o;
    #pragma unroll
    for (int e = 0; e < 8; e++) o[e] = (bf16_t)s[e];
    *(bf16x8*)&t[i] = o;
}

// ---- GEMM2: out[8192][4096] = SCALE*dB * (t @ Bb^T) ----
// BM=64, BN=64, full K=256 staged ONCE -> single barrier per block.
// grid (128,64)=8192 blocks, 64 KB LDS -> 2 blocks/CU, 32 rounds/CU for
// inter-block latency overlap. 4 waves 2x2, wave tile 32x32.
// Rows are 32 slots of 16B; swizzle slot ^= (row&7) (inverse-applied to the
// async16 global source; XOR of low-3 slot bits stays within a 128B line).
__global__ __launch_bounds__(256) void gemm2(const bf16_t* __restrict__ t,
                                             const bf16_t* __restrict__ Bb,
                                             const float* __restrict__ dB,
                                             float* __restrict__ out) {
    __shared__ bf16_t sT[64 * 256];   // 32 KB
    __shared__ bf16_t sB[64 * 256];   // 32 KB
    const int tid = threadIdx.x;
    const int lane = tid & 63, wave = tid >> 6;
    const int wm = wave >> 1, wn = wave & 1;
    const int l15 = lane & 15, quad = lane >> 4;
    const int bm = blockIdx.x * 64;
    const int bn = blockIdx.y * 64;

    // stage everything: 64 rows x 32 slots each for T and B (8 passes each)
    #pragma unroll
    for (int c = 0; c < 8; c++) {
        int idx = c * 256 + tid;
        int row = idx >> 5, sl = idx & 31;
        int src = ((sl ^ (row & 7)) << 3);
        async16(&t[(size_t)(bm + row) * RANK + src], &sT[idx * 8]);
        async16(&Bb[(size_t)(bn + row) * RANK + src], &sB[idx * 8]);
    }
    __syncthreads();

    f32x4 acc[2][2];
    const f32x4 zero = {0.f, 0.f, 0.f, 0.f};
    #pragma unroll
    for (int i = 0; i < 2; i++)
        #pragma unroll
        for (int j = 0; j < 2; j++) acc[i][j] = zero;

    #pragma unroll
    for (int ks = 0; ks < 8; ks++) {   // K=256 in steps of 32
        bf16x8 af[2], bfr[2];
        #pragma unroll
        for (int i = 0; i < 2; i++) {
            int row = wm * 32 + i * 16 + l15;
            int slot = ((ks << 2) | quad) ^ (row & 7);
            af[i] = *(const bf16x8*)&sT[row * 256 + slot * 8];
        }
        #pragma unroll
        for (int j = 0; j < 2; j++) {
            int row = wn * 32 + j * 16 + l15;
            int slot = ((ks << 2) | quad) ^ (row & 7);
            bfr[j] = *(const bf16x8*)&sB[row * 256 + slot * 8];
        }
        #pragma unroll
        for (int i = 0; i < 2; i++)
            #pragma unroll
            for (int j = 0; j < 2; j++)
                acc[i][j] = __builtin_amdgcn_mfma_f32_16x16x32_bf16(bfr[j], af[i], acc[i][j], 0, 0, 0);
    }

    #pragma unroll
    for (int i = 0; i < 2; i++) {
        int row = bm + wm * 32 + i * 16 + l15;
        #pragma unroll
        for (int j = 0; j < 2; j++) {
            int col = bn + wn * 32 + j * 16 + quad * 4;
            f32x4 db = *(const f32x4*)&dB[col];
            f32x4 o;
            #pragma unroll
            for (int r = 0; r < 4; r++) o[r] = db[r] * SCALE_F * acc[i][j][r];
            *(f32x4*)&out[(size_t)row * N_OUT + col] = o;
        }
    }
}

extern "C" void kernel_launch(void* const* d_in, const int* in_sizes, int n_in,
                              void* d_out, int out_size, void* d_ws, size_t ws_size,
                              hipStream_t stream) {
    const float* x  = (const float*)d_in[0];
    const float* A  = (const float*)d_in[1];
    const float* B  = (const float*)d_in[2];
    const float* dA = (const float*)d_in[3];
    const float* dB = (const float*)d_in[4];
    float* out = (float*)d_out;

    char* ws = (char*)d_ws;
    bf16_t* Ab   = (bf16_t*)ws;                       // 2 MB
    bf16_t* Bb   = (bf16_t*)(ws + (1u << 21));        // 2 MB
    bf16_t* tt   = (bf16_t*)(ws + (1u << 22));        // 4 MB
    bf16_t* part = (bf16_t*)(ws + (1u << 23));        // 4 * 4 MB = 16 MB

    conv_AB<<<2048, 256, 0, stream>>>(A, dA, B, Ab, Bb);
    gemm1<<<dim3(128, S_SPLIT), 256, 0, stream>>>(x, Ab, part);
    reduce_t<<<1024, 256, 0, stream>>>(part, tt);
    gemm2<<<dim3(128, 64), 256, 0, stream>>>(tt, Bb, dB, out);
}

// Round 4
// 321.498 us; speedup vs baseline: 1.0530x; 1.0530x over previous
//
#include <hip/hip_runtime.h>
#include <hip/hip_bf16.h>

// VeRA: out = SCALE * d_B[o] * ((x @ (d_A*A)^T) @ B^T)
// GEMM1 (split-K=4): part[s] = x @ Ab^T over K-chunk  (M=8192,N=256,K=1024 each)
// reduce: t = bf16(sum_s part[s])
// GEMM2: out = SCALE*d_B * (t @ Bb^T)  (M=8192,N=4096,K=256)
//
// R4: TRUE counted-vmcnt pipeline (T3+T4). Raw s_barrier (no vmcnt drain),
// inline-asm s_waitcnt vmcnt(N) so next-tile async16 loads stay in flight
// across barriers. All K-loop VMEM is async16 (x staged as raw f32, cvt at
// read). BK=32, small LDS (32/24 KB) -> 4 blocks/CU, 16 waves/CU.

#define SCALE_F 0.125f
#define M_TOT 8192
#define K_IN 4096
#define RANK 256
#define N_OUT 4096
#define S_SPLIT 4
#define KC 1024   // K_IN / S_SPLIT

typedef __bf16 bf16_t;
typedef __bf16 bf16x8 __attribute__((ext_vector_type(8)));
typedef __bf16 bf16x4 __attribute__((ext_vector_type(4)));
typedef float f32x4 __attribute__((ext_vector_type(4)));

typedef __attribute__((address_space(3))) unsigned int lds_u32_t;
typedef const __attribute__((address_space(1))) unsigned int glob_u32_t;

__device__ __forceinline__ void async16(const void* g, void* l) {
    __builtin_amdgcn_global_load_lds((glob_u32_t*)g, (lds_u32_t*)l, 16, 0, 0);
}

// ---- convert A (fold d_A) and B to bf16, fused ----
__global__ __launch_bounds__(256) void conv_AB(const float* __restrict__ A,
                                               const float* __restrict__ dA,
                                               const float* __restrict__ B,
                                               bf16_t* __restrict__ Ab,
                                               bf16_t* __restrict__ Bb) {
    int b = blockIdx.x;
    if (b < 1024) {
        int idx = b * 256 + threadIdx.x;
        float4 v = ((const float4*)A)[idx];
        float s = dA[idx >> 10];
        bf16x4 o;
        o.x = (bf16_t)(v.x * s); o.y = (bf16_t)(v.y * s);
        o.z = (bf16_t)(v.z * s); o.w = (bf16_t)(v.w * s);
        ((bf16x4*)Ab)[idx] = o;
    } else {
        int idx = (b - 1024) * 256 + threadIdx.x;
        float4 v = ((const float4*)B)[idx];
        bf16x4 o;
        o.x = (bf16_t)v.x; o.y = (bf16_t)v.y;
        o.z = (bf16_t)v.z; o.w = (bf16_t)v.w;
        ((bf16x4*)Bb)[idx] = o;
    }
}

// ---- GEMM1: part[z][8192][256] = x(fp32) @ Ab^T over K-chunk z ----
// BM=64, BN=128, BK=32. grid (128,2,4)=1024 blocks = 4/CU (32 KB LDS).
// 4 waves 2x2, wave tile 32x64: 8 MFMA per k-step.
// sX raw f32 via async16 (8-slot rows, slot^=(row&7), source-pre-swizzled);
// sA bf16 (4-slot rows, slot^=((row>>1)&3)). cvt f32->bf16 at fragment read.
// Pipeline: 2-deep ring, counted vmcnt(4) + raw s_barrier (NO drain).
__global__ __launch_bounds__(256, 4) void gemm1(const float* __restrict__ x,
                                                const bf16_t* __restrict__ Ab,
                                                bf16_t* __restrict__ part) {
    __shared__ float  sXf[2][64 * 32];   // 8 KB each
    __shared__ bf16_t sA[2][128 * 32];   // 8 KB each; total 32 KB
    const int tid = threadIdx.x;
    const int lane = tid & 63, wave = tid >> 6;
    const int wm = wave >> 1, wn = wave & 1;
    const int l15 = lane & 15, quad = lane >> 4;
    const int bm = blockIdx.x * 64;
    const int bn = blockIdx.y * 128;
    const int k0 = blockIdx.z * KC;

    f32x4 acc[2][4];
    const f32x4 zero = {0.f, 0.f, 0.f, 0.f};
    #pragma unroll
    for (int i = 0; i < 2; i++)
        #pragma unroll
        for (int j = 0; j < 4; j++) acc[i][j] = zero;

    // 4 async16 per thread per stage (2 sX + 2 sA)
    auto stage = [&](int b, int ts) {
        const int kk = k0 + ts * 32;
        #pragma unroll
        for (int c = 0; c < 2; c++) {          // sX: 64 rows x 8 slots of 4 f32
            int idx = c * 256 + tid;
            int row = idx >> 3, sl = idx & 7;
            async16(&x[(size_t)(bm + row) * K_IN + kk + ((sl ^ (row & 7)) << 2)],
                    &sXf[b][idx * 4]);
        }
        #pragma unroll
        for (int c = 0; c < 2; c++) {          // sA: 128 rows x 4 slots of 8 bf16
            int idx = c * 256 + tid;
            int row = idx >> 2, sl = idx & 3;
            async16(&Ab[(size_t)(bn + row) * K_IN + kk + ((sl ^ ((row >> 1) & 3)) << 3)],
                    &sA[b][idx * 8]);
        }
    };
    auto compute = [&](int b) {
        bf16x8 af[2], bfr[4];
        #pragma unroll
        for (int i = 0; i < 2; i++) {
            int row = wm * 32 + i * 16 + l15;
            f32x4 v0 = *(const f32x4*)&sXf[b][row * 32 + ((((quad << 1) | 0) ^ (row & 7)) << 2)];
            f32x4 v1 = *(const f32x4*)&sXf[b][row * 32 + ((((quad << 1) | 1) ^ (row & 7)) << 2)];
            bf16x8 t;
            #pragma unroll
            for (int e = 0; e < 4; e++) { t[e] = (bf16_t)v0[e]; t[e + 4] = (bf16_t)v1[e]; }
            af[i] = t;
        }
        #pragma unroll
        for (int j = 0; j < 4; j++) {
            int row = wn * 64 + j * 16 + l15;
            bfr[j] = *(const bf16x8*)&sA[b][row * 32 + ((quad ^ ((row >> 1) & 3)) << 3)];
        }
        // swapped operands: lane&15 = m-row, quad*4+r = n-col
        #pragma unroll
        for (int i = 0; i < 2; i++)
            #pragma unroll
            for (int j = 0; j < 4; j++)
                acc[i][j] = __builtin_amdgcn_mfma_f32_16x16x32_bf16(bfr[j], af[i], acc[i][j], 0, 0, 0);
    };

    const int NT = KC / 32;   // 32 k-steps
    stage(0, 0);
    stage(1, 1);
    int cur = 0;
    for (int t = 0; t < NT - 2; ++t) {
        asm volatile("s_waitcnt vmcnt(4)" ::: "memory");  // tile t landed; t+1 in flight
        __builtin_amdgcn_s_barrier();
        compute(cur);
        __builtin_amdgcn_s_barrier();                     // all waves done reading cur
        stage(cur, t + 2);                                // refill cur; stays in flight
        cur ^= 1;
    }
    asm volatile("s_waitcnt vmcnt(4)" ::: "memory");      // tile NT-2 landed
    __builtin_amdgcn_s_barrier();
    compute(cur);
    cur ^= 1;
    asm volatile("s_waitcnt vmcnt(0)" ::: "memory");      // tile NT-1 landed
    __builtin_amdgcn_s_barrier();
    compute(cur);

    bf16_t* p = part + (size_t)blockIdx.z * (M_TOT * RANK);
    #pragma unroll
    for (int i = 0; i < 2; i++) {
        int row = bm + wm * 32 + i * 16 + l15;
        #pragma unroll
        for (int j = 0; j < 4; j++) {
            int col = bn + wn * 64 + j * 16 + quad * 4;
            bf16x4 o;
            #pragma unroll
            for (int r = 0; r < 4; r++) o[r] = (bf16_t)acc[i][j][r];
            *(bf16x4*)&p[(size_t)row * RANK + col] = o;
        }
    }
}

// ---- reduce: t = bf16(sum_z part[z]) ----
__global__ __launch_bounds__(256) void reduce_t(const bf16_t* __restrict__ part,
                                                bf16_t* __restrict__ t) {
    int i = (blockIdx.x * 256 + threadIdx.x) * 8;
    float s[8] = {0.f, 0.f, 0.f, 0.f, 0.f, 0.f, 0.f, 0.f};
    #pragma unroll
    for (int z = 0; z < S_SPLIT; z++) {
        bf16x8 v = *(const bf16x8*)&part[(size_t)z * M_TOT * RANK + i];
        #pragma unroll
        for (int e = 0; e < 8; e++) s[e] += (float)v[e];
    }
    bf16x8 o;
    #pragma unroll
    for (int e = 0; e < 8; e++) o[e] = (bf16_t)s[e];
    *(bf16x8*)&t[i] = o;
}

// ---- GEMM2: out[8192][4096] = SCALE*dB * (t @ Bb^T) ----
// BM=128, BN=64, BK=32, 8 k-steps. grid (64,64)=4096 blocks, 24 KB LDS.
// 4 waves 2x2, wave tile 64x32: 8 MFMA per k-step. Same counted-vmcnt ring.
__global__ __launch_bounds__(256, 4) void gemm2(const bf16_t* __restrict__ t,
                                                const bf16_t* __restrict__ Bb,
                                                const float* __restrict__ dB,
                                                float* __restrict__ out) {
    __shared__ bf16_t sT[2][128 * 32];   // 8 KB each
    __shared__ bf16_t sB[2][64 * 32];    // 4 KB each; total 24 KB
    const int tid = threadIdx.x;
    const int lane = tid & 63, wave = tid >> 6;
    const int wm = wave >> 1, wn = wave & 1;
    const int l15 = lane & 15, quad = lane >> 4;
    const int bm = blockIdx.x * 128;
    const int bn = blockIdx.y * 64;

    f32x4 acc[4][2];
    const f32x4 zero = {0.f, 0.f, 0.f, 0.f};
    #pragma unroll
    for (int i = 0; i < 4; i++)
        #pragma unroll
        for (int j = 0; j < 2; j++) acc[i][j] = zero;

    // 3 async16 per thread per stage (2 sT + 1 sB)
    auto stage = [&](int b, int ts) {
        const int kt = ts * 32;
        #pragma unroll
        for (int c = 0; c < 2; c++) {          // sT: 128 rows x 4 slots
            int idx = c * 256 + tid;
            int row = idx >> 2, sl = idx & 3;
            async16(&t[(size_t)(bm + row) * RANK + kt + ((sl ^ ((row >> 1) & 3)) << 3)],
                    &sT[b][idx * 8]);
        }
        {                                      // sB: 64 rows x 4 slots
            int row = tid >> 2, sl = tid & 3;
            async16(&Bb[(size_t)(bn + row) * RANK + kt + ((sl ^ ((row >> 1) & 3)) << 3)],
                    &sB[b][tid * 8]);
        }
    };
    auto compute = [&](int b) {
        bf16x8 af[4], bfr[2];
        #pragma unroll
        for (int i = 0; i < 4; i++) {
            int row = wm * 64 + i * 16 + l15;
            af[i] = *(const bf16x8*)&sT[b][row * 32 + ((quad ^ ((row >> 1) & 3)) << 3)];
        }
        #pragma unroll
        for (int j = 0; j < 2; j++) {
            int row = wn * 32 + j * 16 + l15;
            bfr[j] = *(const bf16x8*)&sB[b][row * 32 + ((quad ^ ((row >> 1) & 3)) << 3)];
        }
        #pragma unroll
        for (int i = 0; i < 4; i++)
            #pragma unroll
            for (int j = 0; j < 2; j++)
                acc[i][j] = __builtin_amdgcn_mfma_f32_16x16x32_bf16(bfr[j], af[i], acc[i][j], 0, 0, 0);
    };

    const int NT = RANK / 32;   // 8 k-steps
    stage(0, 0);
    stage(1, 1);
    int cur = 0;
    #pragma unroll
    for (int t = 0; t < NT - 2; ++t) {
        asm volatile("s_waitcnt vmcnt(3)" ::: "memory");
        __builtin_amdgcn_s_barrier();
        compute(cur);
        __builtin_amdgcn_s_barrier();
        stage(cur, t + 2);
        cur ^= 1;
    }
    asm volatile("s_waitcnt vmcnt(3)" ::: "memory");
    __builtin_amdgcn_s_barrier();
    compute(cur);
    cur ^= 1;
    asm volatile("s_waitcnt vmcnt(0)" ::: "memory");
    __builtin_amdgcn_s_barrier();
    compute(cur);

    #pragma unroll
    for (int i = 0; i < 4; i++) {
        int row = bm + wm * 64 + i * 16 + l15;
        #pragma unroll
        for (int j = 0; j < 2; j++) {
            int col = bn + wn * 32 + j * 16 + quad * 4;
            f32x4 db = *(const f32x4*)&dB[col];
            f32x4 o;
            #pragma unroll
            for (int r = 0; r < 4; r++) o[r] = db[r] * SCALE_F * acc[i][j][r];
            *(f32x4*)&out[(size_t)row * N_OUT + col] = o;
        }
    }
}

extern "C" void kernel_launch(void* const* d_in, const int* in_sizes, int n_in,
                              void* d_out, int out_size, void* d_ws, size_t ws_size,
                              hipStream_t stream) {
    const float* x  = (const float*)d_in[0];
    const float* A  = (const float*)d_in[1];
    const float* B  = (const float*)d_in[2];
    const float* dA = (const float*)d_in[3];
    const float* dB = (const float*)d_in[4];
    float* out = (float*)d_out;

    char* ws = (char*)d_ws;
    bf16_t* Ab   = (bf16_t*)ws;                       // 2 MB
    bf16_t* Bb   = (bf16_t*)(ws + (1u << 21));        // 2 MB
    bf16_t* tt   = (bf16_t*)(ws + (1u << 22));        // 4 MB
    bf16_t* part = (bf16_t*)(ws + (1u << 23));        // 4 * 4 MB = 16 MB

    conv_AB<<<2048, 256, 0, stream>>>(A, dA, B, Ab, Bb);
    gemm1<<<dim3(128, 2, S_SPLIT), 256, 0, stream>>>(x, Ab, part);
    reduce_t<<<1024, 256, 0, stream>>>(part, tt);
    gemm2<<<dim3(64, 64), 256, 0, stream>>>(tt, Bb, dB, out);
}

// Round 5
// 312.190 us; speedup vs baseline: 1.0844x; 1.0298x over previous
//
#include <hip/hip_runtime.h>
#include <hip/hip_bf16.h>

// VeRA: out = SCALE * d_B[o] * ((x @ (d_A*A)^T) @ B^T)
// GEMM1 (split-K=4): part[s] = x @ Ab^T over K-chunk  (M=8192,N=256,K=1024 each)
// reduce: t = bf16(sum_s part[s])
// GEMM2: out = SCALE*d_B * (t @ Bb^T)  (M=8192,N=4096,K=256)
//
// R5: traffic-model round. gemm1/gemm2 were delivery-BW-bound at ~6.2 TB/s
// logical (536 MB each). gemm1: BN=256 (x staged once) + z-per-XCD-pair
// mapping (A-chunk L2-resident) -> L3-side traffic 134 MB. gemm2: R4
// structure + 2-D XCD tiling (t-slice 2MB + B-slice 0.5MB fit per-XCD L2)
// -> L3-side ~180 MB. Counted-vmcnt rings (R4) kept in both.

#define SCALE_F 0.125f
#define M_TOT 8192
#define K_IN 4096
#define RANK 256
#define N_OUT 4096
#define S_SPLIT 4
#define KC 1024   // K_IN / S_SPLIT

typedef __bf16 bf16_t;
typedef __bf16 bf16x8 __attribute__((ext_vector_type(8)));
typedef __bf16 bf16x4 __attribute__((ext_vector_type(4)));
typedef float f32x4 __attribute__((ext_vector_type(4)));

typedef __attribute__((address_space(3))) unsigned int lds_u32_t;
typedef const __attribute__((address_space(1))) unsigned int glob_u32_t;

__device__ __forceinline__ void async16(const void* g, void* l) {
    __builtin_amdgcn_global_load_lds((glob_u32_t*)g, (lds_u32_t*)l, 16, 0, 0);
}

// ---- convert A (fold d_A) and B to bf16, fused ----
__global__ __launch_bounds__(256) void conv_AB(const float* __restrict__ A,
                                               const float* __restrict__ dA,
                                               const float* __restrict__ B,
                                               bf16_t* __restrict__ Ab,
                                               bf16_t* __restrict__ Bb) {
    int b = blockIdx.x;
    if (b < 1024) {
        int idx = b * 256 + threadIdx.x;
        float4 v = ((const float4*)A)[idx];
        float s = dA[idx >> 10];
        bf16x4 o;
        o.x = (bf16_t)(v.x * s); o.y = (bf16_t)(v.y * s);
        o.z = (bf16_t)(v.z * s); o.w = (bf16_t)(v.w * s);
        ((bf16x4*)Ab)[idx] = o;
    } else {
        int idx = (b - 1024) * 256 + threadIdx.x;
        float4 v = ((const float4*)B)[idx];
        bf16x4 o;
        o.x = (bf16_t)v.x; o.y = (bf16_t)v.y;
        o.z = (bf16_t)v.z; o.w = (bf16_t)v.w;
        ((bf16x4*)Bb)[idx] = o;
    }
}

// ---- GEMM1: part[z][8192][256] = x(fp32) @ Ab^T over K-chunk z ----
// BM=64, BN=256 (full rank: x staged ONCE), BK=32. 512 blocks, 2/CU.
// Block map: xcd = wg&7, z = xcd>>1, m = (wg>>3) | ((xcd&1)<<6)  -> each
// XCD-pair works one z-chunk; its 0.5 MB A-chunk stays L2-resident.
// 4 waves 2x2, wave tile 32x128: 16 MFMA/k-step. sX raw f32 via async16
// (cvt at read); counted vmcnt(6) ring, raw s_barrier (no drain). 48 KB LDS.
__global__ __launch_bounds__(256, 2) void gemm1(const float* __restrict__ x,
                                                const bf16_t* __restrict__ Ab,
                                                bf16_t* __restrict__ part) {
    __shared__ float  sXf[2][64 * 32];   // 8 KB each
    __shared__ bf16_t sA[2][256 * 32];   // 16 KB each; total 48 KB
    const int tid = threadIdx.x;
    const int lane = tid & 63, wave = tid >> 6;
    const int wm = wave >> 1, wn = wave & 1;
    const int l15 = lane & 15, quad = lane >> 4;

    const int wg  = blockIdx.x;
    const int xcd = wg & 7;
    const int z   = xcd >> 1;
    const int m   = (wg >> 3) | ((xcd & 1) << 6);   // [0,128)
    const int bm  = m * 64;
    const int k0  = z * KC;

    f32x4 acc[2][8];
    const f32x4 zero = {0.f, 0.f, 0.f, 0.f};
    #pragma unroll
    for (int i = 0; i < 2; i++)
        #pragma unroll
        for (int j = 0; j < 8; j++) acc[i][j] = zero;

    // 6 async16 per thread per stage (2 sX + 4 sA)
    auto stage = [&](int b, int ts) {
        const int kk = k0 + ts * 32;
        #pragma unroll
        for (int c = 0; c < 2; c++) {          // sX: 64 rows x 8 slots of 4 f32
            int idx = c * 256 + tid;
            int row = idx >> 3, sl = idx & 7;
            async16(&x[(size_t)(bm + row) * K_IN + kk + ((sl ^ (row & 7)) << 2)],
                    &sXf[b][idx * 4]);
        }
        #pragma unroll
        for (int c = 0; c < 4; c++) {          // sA: 256 rows x 4 slots of 8 bf16
            int idx = c * 256 + tid;
            int row = idx >> 2, sl = idx & 3;
            async16(&Ab[(size_t)row * K_IN + kk + ((sl ^ ((row >> 1) & 3)) << 3)],
                    &sA[b][idx * 8]);
        }
    };
    auto compute = [&](int b) {
        bf16x8 af[2], bfr[8];
        #pragma unroll
        for (int i = 0; i < 2; i++) {
            int row = wm * 32 + i * 16 + l15;
            f32x4 v0 = *(const f32x4*)&sXf[b][row * 32 + ((((quad << 1) | 0) ^ (row & 7)) << 2)];
            f32x4 v1 = *(const f32x4*)&sXf[b][row * 32 + ((((quad << 1) | 1) ^ (row & 7)) << 2)];
            bf16x8 t;
            #pragma unroll
            for (int e = 0; e < 4; e++) { t[e] = (bf16_t)v0[e]; t[e + 4] = (bf16_t)v1[e]; }
            af[i] = t;
        }
        #pragma unroll
        for (int j = 0; j < 8; j++) {
            int row = wn * 128 + j * 16 + l15;
            bfr[j] = *(const bf16x8*)&sA[b][row * 32 + ((quad ^ ((row >> 1) & 3)) << 3)];
        }
        // swapped operands: lane&15 = m-row, quad*4+r = n-col
        #pragma unroll
        for (int i = 0; i < 2; i++)
            #pragma unroll
            for (int j = 0; j < 8; j++)
                acc[i][j] = __builtin_amdgcn_mfma_f32_16x16x32_bf16(bfr[j], af[i], acc[i][j], 0, 0, 0);
    };

    const int NT = KC / 32;   // 32 k-steps
    stage(0, 0);
    stage(1, 1);
    int cur = 0;
    for (int t = 0; t < NT - 2; ++t) {
        asm volatile("s_waitcnt vmcnt(6)" ::: "memory");  // tile t landed; t+1 in flight
        __builtin_amdgcn_s_barrier();
        compute(cur);
        __builtin_amdgcn_s_barrier();                     // all waves done reading cur
        stage(cur, t + 2);                                // refill; stays in flight
        cur ^= 1;
    }
    asm volatile("s_waitcnt vmcnt(6)" ::: "memory");
    __builtin_amdgcn_s_barrier();
    compute(cur);
    cur ^= 1;
    asm volatile("s_waitcnt vmcnt(0)" ::: "memory");
    __builtin_amdgcn_s_barrier();
    compute(cur);

    bf16_t* p = part + (size_t)z * (M_TOT * RANK);
    #pragma unroll
    for (int i = 0; i < 2; i++) {
        int row = bm + wm * 32 + i * 16 + l15;
        #pragma unroll
        for (int j = 0; j < 8; j++) {
            int col = wn * 128 + j * 16 + quad * 4;
            bf16x4 o;
            #pragma unroll
            for (int r = 0; r < 4; r++) o[r] = (bf16_t)acc[i][j][r];
            *(bf16x4*)&p[(size_t)row * RANK + col] = o;
        }
    }
}

// ---- reduce: t = bf16(sum_z part[z]) ----
__global__ __launch_bounds__(256) void reduce_t(const bf16_t* __restrict__ part,
                                                bf16_t* __restrict__ t) {
    int i = (blockIdx.x * 256 + threadIdx.x) * 8;
    float s[8] = {0.f, 0.f, 0.f, 0.f, 0.f, 0.f, 0.f, 0.f};
    #pragma unroll
    for (int z = 0; z < S_SPLIT; z++) {
        bf16x8 v = *(const bf16x8*)&part[(size_t)z * M_TOT * RANK + i];
        #pragma unroll
        for (int e = 0; e < 8; e++) s[e] += (float)v[e];
    }
    bf16x8 o;
    #pragma unroll
    for (int e = 0; e < 8; e++) o[e] = (bf16_t)s[e];
    *(bf16x8*)&t[i] = o;
}

// ---- GEMM2: out[8192][4096] = SCALE*dB * (t @ Bb^T) ----
// BM=128, BN=64, BK=32, 8 k-steps. 4096 blocks; 2-D XCD tiling:
// xcd -> (m-half, n-quarter): t-slice 2 MB + B-slice 0.5 MB fit per-XCD L2.
// 4 waves 2x2, wave tile 64x32. Counted-vmcnt ring as R4. 24 KB LDS.
__global__ __launch_bounds__(256, 4) void gemm2(const bf16_t* __restrict__ t,
                                                const bf16_t* __restrict__ Bb,
                                                const float* __restrict__ dB,
                                                float* __restrict__ out) {
    __shared__ bf16_t sT[2][128 * 32];   // 8 KB each
    __shared__ bf16_t sB[2][64 * 32];    // 4 KB each; total 24 KB
    const int tid = threadIdx.x;
    const int lane = tid & 63, wave = tid >> 6;
    const int wm = wave >> 1, wn = wave & 1;
    const int l15 = lane & 15, quad = lane >> 4;

    const int wg  = blockIdx.x;
    const int xcd = wg & 7;
    const int w   = wg >> 3;                       // [0,512)
    const int mb  = (xcd & 1) * 32 + (w & 31);     // [0,64)
    const int nb  = (xcd >> 1) * 16 + (w >> 5);    // [0,64)
    const int bm  = mb * 128;
    const int bn  = nb * 64;

    f32x4 acc[4][2];
    const f32x4 zero = {0.f, 0.f, 0.f, 0.f};
    #pragma unroll
    for (int i = 0; i < 4; i++)
        #pragma unroll
        for (int j = 0; j < 2; j++) acc[i][j] = zero;

    // 3 async16 per thread per stage (2 sT + 1 sB)
    auto stage = [&](int b, int ts) {
        const int kt = ts * 32;
        #pragma unroll
        for (int c = 0; c < 2; c++) {          // sT: 128 rows x 4 slots
            int idx = c * 256 + tid;
            int row = idx >> 2, sl = idx & 3;
            async16(&t[(size_t)(bm + row) * RANK + kt + ((sl ^ ((row >> 1) & 3)) << 3)],
                    &sT[b][idx * 8]);
        }
        {                                      // sB: 64 rows x 4 slots
            int row = tid >> 2, sl = tid & 3;
            async16(&Bb[(size_t)(bn + row) * RANK + kt + ((sl ^ ((row >> 1) & 3)) << 3)],
                    &sB[b][tid * 8]);
        }
    };
    auto compute = [&](int b) {
        bf16x8 af[4], bfr[2];
        #pragma unroll
        for (int i = 0; i < 4; i++) {
            int row = wm * 64 + i * 16 + l15;
            af[i] = *(const bf16x8*)&sT[b][row * 32 + ((quad ^ ((row >> 1) & 3)) << 3)];
        }
        #pragma unroll
        for (int j = 0; j < 2; j++) {
            int row = wn * 32 + j * 16 + l15;
            bfr[j] = *(const bf16x8*)&sB[b][row * 32 + ((quad ^ ((row >> 1) & 3)) << 3)];
        }
        #pragma unroll
        for (int i = 0; i < 4; i++)
            #pragma unroll
            for (int j = 0; j < 2; j++)
                acc[i][j] = __builtin_amdgcn_mfma_f32_16x16x32_bf16(bfr[j], af[i], acc[i][j], 0, 0, 0);
    };

    const int NT = RANK / 32;   // 8 k-steps
    stage(0, 0);
    stage(1, 1);
    int cur = 0;
    #pragma unroll
    for (int t = 0; t < NT - 2; ++t) {
        asm volatile("s_waitcnt vmcnt(3)" ::: "memory");
        __builtin_amdgcn_s_barrier();
        compute(cur);
        __builtin_amdgcn_s_barrier();
        stage(cur, t + 2);
        cur ^= 1;
    }
    asm volatile("s_waitcnt vmcnt(3)" ::: "memory");
    __builtin_amdgcn_s_barrier();
    compute(cur);
    cur ^= 1;
    asm volatile("s_waitcnt vmcnt(0)" ::: "memory");
    __builtin_amdgcn_s_barrier();
    compute(cur);

    #pragma unroll
    for (int i = 0; i < 4; i++) {
        int row = bm + wm * 64 + i * 16 + l15;
        #pragma unroll
        for (int j = 0; j < 2; j++) {
            int col = bn + wn * 32 + j * 16 + quad * 4;
            f32x4 db = *(const f32x4*)&dB[col];
            f32x4 o;
            #pragma unroll
            for (int r = 0; r < 4; r++) o[r] = db[r] * SCALE_F * acc[i][j][r];
            *(f32x4*)&out[(size_t)row * N_OUT + col] = o;
        }
    }
}

extern "C" void kernel_launch(void* const* d_in, const int* in_sizes, int n_in,
                              void* d_out, int out_size, void* d_ws, size_t ws_size,
                              hipStream_t stream) {
    const float* x  = (const float*)d_in[0];
    const float* A  = (const float*)d_in[1];
    const float* B  = (const float*)d_in[2];
    const float* dA = (const float*)d_in[3];
    const float* dB = (const float*)d_in[4];
    float* out = (float*)d_out;

    char* ws = (char*)d_ws;
    bf16_t* Ab   = (bf16_t*)ws;                       // 2 MB
    bf16_t* Bb   = (bf16_t*)(ws + (1u << 21));        // 2 MB
    bf16_t* tt   = (bf16_t*)(ws + (1u << 22));        // 4 MB
    bf16_t* part = (bf16_t*)(ws + (1u << 23));        // 4 * 4 MB = 16 MB

    conv_AB<<<2048, 256, 0, stream>>>(A, dA, B, Ab, Bb);
    gemm1<<<512, 256, 0, stream>>>(x, Ab, part);
    reduce_t<<<1024, 256, 0, stream>>>(part, tt);
    gemm2<<<4096, 256, 0, stream>>>(tt, Bb, dB, out);
}